// Round 1
// baseline (341.422 us; speedup 1.0000x reference)
//
#include <hip/hip_runtime.h>
#include <hip/hip_bf16.h>

typedef __attribute__((ext_vector_type(8))) short short8;
typedef __attribute__((ext_vector_type(4))) float f32x4;

#define P64 64
#define FDIM 16384   // 32*32*16
#define OUT0 16777216  // elements in `out` before attn chunk

// fp32 -> bf16, round-to-nearest-even (inputs are normal randoms, no NaN path needed)
__device__ __forceinline__ unsigned short f2bf(float x) {
    unsigned int u = __float_as_uint(x);
    u += 0x7FFFu + ((u >> 16) & 1u);
    return (unsigned short)(u >> 16);
}

__device__ __forceinline__ short8 pack8(float4 v0, float4 v1) {
    short8 r;
    r[0] = (short)f2bf(v0.x); r[1] = (short)f2bf(v0.y);
    r[2] = (short)f2bf(v0.z); r[3] = (short)f2bf(v0.w);
    r[4] = (short)f2bf(v1.x); r[5] = (short)f2bf(v1.y);
    r[6] = (short)f2bf(v1.z); r[7] = (short)f2bf(v1.w);
    return r;
}

// ---------------------------------------------------------------------------
// Kernel 1: partial Q.K^T.  grid = (16 kchunks, 16 bn), block = 256 (4 waves).
// Each wave owns a 256-wide k slice and computes a full 64x64 partial score
// matrix with 16x16x32 bf16 MFMAs, written to partials[bn][slice][p][q].
// ---------------------------------------------------------------------------
__global__ __launch_bounds__(256) void qk_kernel(
        const float* __restrict__ Q, const float* __restrict__ K,
        float* __restrict__ partials) {
    const int bn   = blockIdx.y;
    const int wave = threadIdx.x >> 6;
    const int lane = threadIdx.x & 63;
    const int slice = blockIdx.x * 4 + wave;        // 0..63
    const int kbase0 = slice * 256;
    const int lrow = lane & 15;
    const int lkg  = (lane >> 4) * 8;

    const float* Qb = Q + (size_t)bn * P64 * FDIM;
    const float* Kb = K + (size_t)bn * P64 * FDIM;

    f32x4 acc[4][4];
#pragma unroll
    for (int i = 0; i < 4; i++)
#pragma unroll
        for (int j = 0; j < 4; j++) acc[i][j] = (f32x4){0.f, 0.f, 0.f, 0.f};

#pragma unroll 2
    for (int ks = 0; ks < 256; ks += 32) {
        const int kb = kbase0 + ks + lkg;
        short8 a[4], b[4];
#pragma unroll
        for (int pt = 0; pt < 4; pt++) {
            const float* src = Qb + (size_t)(pt * 16 + lrow) * FDIM + kb;
            a[pt] = pack8(*(const float4*)src, *(const float4*)(src + 4));
        }
#pragma unroll
        for (int qt = 0; qt < 4; qt++) {
            const float* src = Kb + (size_t)(qt * 16 + lrow) * FDIM + kb;
            b[qt] = pack8(*(const float4*)src, *(const float4*)(src + 4));
        }
#pragma unroll
        for (int pt = 0; pt < 4; pt++)
#pragma unroll
            for (int qt = 0; qt < 4; qt++)
                acc[pt][qt] = __builtin_amdgcn_mfma_f32_16x16x32_bf16(
                    a[pt], b[qt], acc[pt][qt], 0, 0, 0);
    }

    float* dst = partials + ((size_t)bn * 64 + slice) * 4096;
#pragma unroll
    for (int pt = 0; pt < 4; pt++)
#pragma unroll
        for (int qt = 0; qt < 4; qt++)
#pragma unroll
            for (int r = 0; r < 4; r++) {
                const int p = pt * 16 + (lane >> 4) * 4 + r;
                const int q = qt * 16 + (lane & 15);
                dst[p * 64 + q] = acc[pt][qt][r];
            }
}

// ---------------------------------------------------------------------------
// Kernel 2: reduce partials over 64 slices, scale by 1/1024, softmax over q,
// write attention weights (fp32) into d_out tail.
// grid = 256, block = 256 (4 waves, one (bn,p) row per wave, lane = q).
// ---------------------------------------------------------------------------
__global__ __launch_bounds__(256) void softmax_kernel(
        const float* __restrict__ partials, float* __restrict__ attn_out) {
    const int wave = threadIdx.x >> 6;
    const int lane = threadIdx.x & 63;
    const int row  = blockIdx.x * 4 + wave;   // 0..1023 = bn*64 + p
    const int bn = row >> 6;
    const int p  = row & 63;

    const float* src = partials + (size_t)bn * 64 * 4096 + p * 64 + lane;
    float s = 0.f;
#pragma unroll 8
    for (int sl = 0; sl < 64; sl++) s += src[(size_t)sl * 4096];
    s *= (1.0f / 1024.0f);

    float m = s;
#pragma unroll
    for (int off = 32; off; off >>= 1) m = fmaxf(m, __shfl_xor(m, off, 64));
    const float e = __expf(s - m);
    float sum = e;
#pragma unroll
    for (int off = 32; off; off >>= 1) sum += __shfl_xor(sum, off, 64);
    attn_out[(size_t)row * 64 + lane] = e / sum;
}

// ---------------------------------------------------------------------------
// Kernel 3: out[b][p][f][n] = sum_q attn[b][n][p][q] * V[b][n][q][f].
// grid = (256 fchunks of 64, 2 b), block = 256 (4 waves; wave owns 16 p rows).
// Loops n inside the block so all 8 n of each output sector are written by
// one block (L2 write-combining).
// ---------------------------------------------------------------------------
__global__ __launch_bounds__(256) void pv_kernel(
        const float* __restrict__ V, const float* __restrict__ attn,
        float* __restrict__ out) {
    const int b  = blockIdx.y;
    const int fc = blockIdx.x * 64;
    const int wave = threadIdx.x >> 6;
    const int lane = threadIdx.x & 63;
    const int pstrip = wave * 16;
    const int lrow = lane & 15;
    const int lg   = lane >> 4;

    for (int n = 0; n < 8; n++) {
        const float* An = attn + (size_t)(b * 8 + n) * 64 * 64;   // [p][q]
        const float* Vn = V + (size_t)(b * 8 + n) * P64 * FDIM;   // [q][f]

        short8 a[2];
#pragma unroll
        for (int kk = 0; kk < 2; kk++) {
            const float* src = An + (size_t)(pstrip + lrow) * 64 + kk * 32 + lg * 8;
            a[kk] = pack8(*(const float4*)src, *(const float4*)(src + 4));
        }

        f32x4 acc[4];
#pragma unroll
        for (int ft = 0; ft < 4; ft++) acc[ft] = (f32x4){0.f, 0.f, 0.f, 0.f};

#pragma unroll
        for (int kk = 0; kk < 2; kk++) {
#pragma unroll
            for (int ft = 0; ft < 4; ft++) {
                // B frag: f = fc + ft*16 + lrow, q = kk*32 + lg*8 + j
                const float* vs = Vn + (size_t)(kk * 32 + lg * 8) * FDIM + fc + ft * 16 + lrow;
                short8 bf;
#pragma unroll
                for (int j = 0; j < 8; j++) bf[j] = (short)f2bf(vs[(size_t)j * FDIM]);
                acc[ft] = __builtin_amdgcn_mfma_f32_16x16x32_bf16(a[kk], bf, acc[ft], 0, 0, 0);
            }
        }

#pragma unroll
        for (int ft = 0; ft < 4; ft++)
#pragma unroll
            for (int r = 0; r < 4; r++) {
                const int p = pstrip + lg * 4 + r;
                const int f = fc + ft * 16 + lrow;
                out[((size_t)(b * 64 + p) * FDIM + f) * 8 + n] = acc[ft][r];
            }
    }
}

extern "C" void kernel_launch(void* const* d_in, const int* in_sizes, int n_in,
                              void* d_out, int out_size, void* d_ws, size_t ws_size,
                              hipStream_t stream) {
    const float* Q = (const float*)d_in[0];
    const float* K = (const float*)d_in[1];
    const float* V = (const float*)d_in[2];
    float* out  = (float*)d_out;
    float* attn = out + OUT0;            // [b][n][p][q] fp32, 65536 elems
    float* partials = (float*)d_ws;      // 16 bn * 64 slices * 4096 fp32 = 16 MB

    qk_kernel<<<dim3(16, 16), 256, 0, stream>>>(Q, K, partials);
    softmax_kernel<<<256, 256, 0, stream>>>(partials, attn);
    pv_kernel<<<dim3(256, 2), 256, 0, stream>>>(V, attn, out);
}

// Round 2
// 272.535 us; speedup vs baseline: 1.2528x; 1.2528x over previous
//
#include <hip/hip_runtime.h>
#include <hip/hip_bf16.h>

typedef __attribute__((ext_vector_type(8))) short short8;
typedef __attribute__((ext_vector_type(4))) float f32x4;

#define P64 64
#define FDIM 16384     // 32*32*16
#define OUT0 16777216  // elements in `out` before attn chunk

// fp32 -> bf16, round-to-nearest-even
__device__ __forceinline__ unsigned short f2bf(float x) {
    unsigned int u = __float_as_uint(x);
    u += 0x7FFFu + ((u >> 16) & 1u);
    return (unsigned short)(u >> 16);
}

__device__ __forceinline__ short8 pack8(float4 v0, float4 v1) {
    short8 r;
    r[0] = (short)f2bf(v0.x); r[1] = (short)f2bf(v0.y);
    r[2] = (short)f2bf(v0.z); r[3] = (short)f2bf(v0.w);
    r[4] = (short)f2bf(v1.x); r[5] = (short)f2bf(v1.y);
    r[6] = (short)f2bf(v1.z); r[7] = (short)f2bf(v1.w);
    return r;
}

// ---------------------------------------------------------------------------
// Kernel 1: partial Q.K^T.  grid = (64 slices, 16 bn), block = 256 (4 waves).
// Block owns a 256-wide k slice; each wave a 64-k quarter. Waves LDS-reduce
// (padded rows, conflict-free) and write one 64x64 partial per block.
// ---------------------------------------------------------------------------
__global__ __launch_bounds__(256) void qk_kernel(
        const float* __restrict__ Q, const float* __restrict__ K,
        float* __restrict__ partials) {
    __shared__ float red[4][64 * 65];
    const int bn    = blockIdx.y;
    const int slice = blockIdx.x;              // 0..63
    const int wave  = threadIdx.x >> 6;
    const int lane  = threadIdx.x & 63;
    const int lrow  = lane & 15;
    const int lg    = lane >> 4;
    const int kbase0 = slice * 256 + wave * 64;

    const float* Qb = Q + (size_t)bn * P64 * FDIM;
    const float* Kb = K + (size_t)bn * P64 * FDIM;

    f32x4 acc[4][4];
#pragma unroll
    for (int i = 0; i < 4; i++)
#pragma unroll
        for (int j = 0; j < 4; j++) acc[i][j] = (f32x4){0.f, 0.f, 0.f, 0.f};

#pragma unroll
    for (int ks = 0; ks < 64; ks += 32) {
        const int kb = kbase0 + ks + lg * 8;
        short8 a[4], b[4];
#pragma unroll
        for (int pt = 0; pt < 4; pt++) {
            const float* src = Qb + (size_t)(pt * 16 + lrow) * FDIM + kb;
            a[pt] = pack8(*(const float4*)src, *(const float4*)(src + 4));
        }
#pragma unroll
        for (int qt = 0; qt < 4; qt++) {
            const float* src = Kb + (size_t)(qt * 16 + lrow) * FDIM + kb;
            b[qt] = pack8(*(const float4*)src, *(const float4*)(src + 4));
        }
#pragma unroll
        for (int pt = 0; pt < 4; pt++)
#pragma unroll
            for (int qt = 0; qt < 4; qt++)
                acc[pt][qt] = __builtin_amdgcn_mfma_f32_16x16x32_bf16(
                    a[pt], b[qt], acc[pt][qt], 0, 0, 0);
    }

    // stash this wave's 64x64 into padded LDS (row stride 65 -> no conflicts)
#pragma unroll
    for (int pt = 0; pt < 4; pt++)
#pragma unroll
        for (int qt = 0; qt < 4; qt++)
#pragma unroll
            for (int r = 0; r < 4; r++) {
                const int p = pt * 16 + lg * 4 + r;
                const int q = qt * 16 + lrow;
                red[wave][p * 65 + q] = acc[pt][qt][r];
            }
    __syncthreads();

    float* dst = partials + ((size_t)bn * 64 + slice) * 4096;
#pragma unroll
    for (int e = threadIdx.x; e < 4096; e += 256) {
        const int p = e >> 6, q = e & 63;
        const int o = p * 65 + q;
        dst[e] = red[0][o] + red[1][o] + red[2][o] + red[3][o];
    }
}

// ---------------------------------------------------------------------------
// Kernel 2: reduce partials over 64 slices, scale, softmax over q,
// write attention weights (fp32) into d_out tail.
// ---------------------------------------------------------------------------
__global__ __launch_bounds__(256) void softmax_kernel(
        const float* __restrict__ partials, float* __restrict__ attn_out) {
    const int wave = threadIdx.x >> 6;
    const int lane = threadIdx.x & 63;
    const int row  = blockIdx.x * 4 + wave;   // 0..1023 = bn*64 + p
    const int bn = row >> 6;
    const int p  = row & 63;

    const float* src = partials + (size_t)bn * 64 * 4096 + p * 64 + lane;
    float s = 0.f;
#pragma unroll 8
    for (int sl = 0; sl < 64; sl++) s += src[(size_t)sl * 4096];
    s *= (1.0f / 1024.0f);

    float m = s;
#pragma unroll
    for (int off = 32; off; off >>= 1) m = fmaxf(m, __shfl_xor(m, off, 64));
    const float e = __expf(s - m);
    float sum = e;
#pragma unroll
    for (int off = 32; off; off >>= 1) sum += __shfl_xor(sum, off, 64);
    attn_out[(size_t)row * 64 + lane] = e / sum;
}

// ---------------------------------------------------------------------------
// Kernel 3: out[b][p][f][n] = sum_q attn[b][n][p][q] * V[b][n][q][f].
// grid = (1024 fchunks of 16, 2 b), block = 256 (4 waves; wave = 16p x 16f).
// All 8 n accumulate in registers; each lane stores one 32B (p,f) sector
// (all 8 n contiguous) -> no write amplification.
// ---------------------------------------------------------------------------
__global__ __launch_bounds__(256) void pv_kernel(
        const float* __restrict__ V, const float* __restrict__ attn,
        float* __restrict__ out) {
    const int b  = blockIdx.y;
    const int fc = blockIdx.x * 16;
    const int wave = threadIdx.x >> 6;
    const int lane = threadIdx.x & 63;
    const int pstrip = wave * 16;
    const int lrow = lane & 15;
    const int lg   = lane >> 4;

    f32x4 acc[8];
#pragma unroll
    for (int n = 0; n < 8; n++) acc[n] = (f32x4){0.f, 0.f, 0.f, 0.f};

#pragma unroll
    for (int n = 0; n < 8; n++) {
        const float* An = attn + (size_t)(b * 8 + n) * 64 * 64;   // [p][q]
        const float* Vn = V + (size_t)(b * 8 + n) * P64 * FDIM;   // [q][f]

#pragma unroll
        for (int kk = 0; kk < 2; kk++) {
            // A frag: p = pstrip + lrow, q = kk*32 + lg*8 + j
            const float* as = An + (size_t)(pstrip + lrow) * 64 + kk * 32 + lg * 8;
            const short8 a = pack8(*(const float4*)as, *(const float4*)(as + 4));
            // B frag: f = fc + lrow, q = kk*32 + lg*8 + j
            const float* vs = Vn + (size_t)(kk * 32 + lg * 8) * FDIM + fc + lrow;
            short8 bf;
#pragma unroll
            for (int j = 0; j < 8; j++) bf[j] = (short)f2bf(vs[(size_t)j * FDIM]);
            acc[n] = __builtin_amdgcn_mfma_f32_16x16x32_bf16(a, bf, acc[n], 0, 0, 0);
        }
    }

#pragma unroll
    for (int r = 0; r < 4; r++) {
        const int p = pstrip + lg * 4 + r;
        float4 w0, w1;
        w0.x = acc[0][r]; w0.y = acc[1][r]; w0.z = acc[2][r]; w0.w = acc[3][r];
        w1.x = acc[4][r]; w1.y = acc[5][r]; w1.z = acc[6][r]; w1.w = acc[7][r];
        float* dst = out + ((size_t)(b * 64 + p) * FDIM + fc + lrow) * 8;
        *(float4*)dst       = w0;
        *(float4*)(dst + 4) = w1;
    }
}

extern "C" void kernel_launch(void* const* d_in, const int* in_sizes, int n_in,
                              void* d_out, int out_size, void* d_ws, size_t ws_size,
                              hipStream_t stream) {
    const float* Q = (const float*)d_in[0];
    const float* K = (const float*)d_in[1];
    const float* V = (const float*)d_in[2];
    float* out  = (float*)d_out;
    float* attn = out + OUT0;            // [b][n][p][q] fp32, 65536 elems
    float* partials = (float*)d_ws;      // 16 bn * 64 slices * 4096 fp32 = 16 MB

    qk_kernel<<<dim3(64, 16), 256, 0, stream>>>(Q, K, partials);
    softmax_kernel<<<256, 256, 0, stream>>>(partials, attn);
    pv_kernel<<<dim3(1024, 2), 256, 0, stream>>>(V, attn, out);
}

// Round 3
// 240.380 us; speedup vs baseline: 1.4203x; 1.1338x over previous
//
#include <hip/hip_runtime.h>
#include <hip/hip_bf16.h>

typedef __attribute__((ext_vector_type(8))) short short8;
typedef __attribute__((ext_vector_type(4))) float f32x4;

#define FDIM 16384     // 32*32*16
#define OUT0 16777216  // elements in `out` before attn chunk
#define NSL  256       // k-slices per bn (64 k each)

// fp32 -> bf16 bits, round-to-nearest-even
__device__ __forceinline__ unsigned short f2bf(float x) {
    unsigned int u = __float_as_uint(x);
    u += 0x7FFFu + ((u >> 16) & 1u);
    return (unsigned short)(u >> 16);
}
__device__ __forceinline__ float bf2f(unsigned short b) {
    return __uint_as_float(((unsigned int)b) << 16);
}
__device__ __forceinline__ short8 pack8(float4 v0, float4 v1) {
    short8 r;
    r[0] = (short)f2bf(v0.x); r[1] = (short)f2bf(v0.y);
    r[2] = (short)f2bf(v0.z); r[3] = (short)f2bf(v0.w);
    r[4] = (short)f2bf(v1.x); r[5] = (short)f2bf(v1.y);
    r[6] = (short)f2bf(v1.z); r[7] = (short)f2bf(v1.w);
    return r;
}

// ---------------------------------------------------------------------------
// K1: partial Q.K^T. grid = (64, 16 bn), block = 256 (4 waves). Each wave owns
// a 64-k slice, computes 64x64 partial scores, writes bf16 partials in
// [bn][p][slice][q] layout (softmax streams it contiguously). No LDS.
// ---------------------------------------------------------------------------
__global__ __launch_bounds__(256, 4) void qk_kernel(
        const float* __restrict__ Q, const float* __restrict__ K,
        unsigned short* __restrict__ partials) {
    const int bn   = blockIdx.y;
    const int wave = threadIdx.x >> 6;
    const int lane = threadIdx.x & 63;
    const int sl   = blockIdx.x * 4 + wave;   // 0..255
    const int lrow = lane & 15;
    const int lg   = lane >> 4;

    const float* Qb = Q + (size_t)bn * 64 * FDIM;
    const float* Kb = K + (size_t)bn * 64 * FDIM;

    f32x4 acc[4][4];
#pragma unroll
    for (int i = 0; i < 4; i++)
#pragma unroll
        for (int j = 0; j < 4; j++) acc[i][j] = (f32x4){0.f, 0.f, 0.f, 0.f};

#pragma unroll
    for (int ks = 0; ks < 64; ks += 32) {
        const int kb = sl * 64 + ks + lg * 8;
        short8 a[4], b[4];
#pragma unroll
        for (int pt = 0; pt < 4; pt++) {
            const float* src = Qb + (size_t)(pt * 16 + lrow) * FDIM + kb;
            a[pt] = pack8(*(const float4*)src, *(const float4*)(src + 4));
        }
#pragma unroll
        for (int qt = 0; qt < 4; qt++) {
            const float* src = Kb + (size_t)(qt * 16 + lrow) * FDIM + kb;
            b[qt] = pack8(*(const float4*)src, *(const float4*)(src + 4));
        }
#pragma unroll
        for (int pt = 0; pt < 4; pt++)
#pragma unroll
            for (int qt = 0; qt < 4; qt++)
                acc[pt][qt] = __builtin_amdgcn_mfma_f32_16x16x32_bf16(
                    a[pt], b[qt], acc[pt][qt], 0, 0, 0);
    }

#pragma unroll
    for (int pt = 0; pt < 4; pt++)
#pragma unroll
        for (int qt = 0; qt < 4; qt++)
#pragma unroll
            for (int r = 0; r < 4; r++) {
                const int p = pt * 16 + lg * 4 + r;
                const int q = qt * 16 + lrow;
                partials[((size_t)(bn * 64 + p) * NSL + sl) * 64 + q] =
                    f2bf(acc[pt][qt][r]);
            }
}

// ---------------------------------------------------------------------------
// K2: per (bn,p) row: sum 256 bf16 partial slices (32 KB contiguous, short8
// loads), scale, softmax over q, write fp32 attn. grid = 1024, block = 256.
// ---------------------------------------------------------------------------
__global__ __launch_bounds__(256) void softmax_kernel(
        const unsigned short* __restrict__ partials, float* __restrict__ attn_out) {
    __shared__ float red[4][64];
    const int row  = blockIdx.x;             // bn*64 + p
    const int wave = threadIdx.x >> 6;
    const int lane = threadIdx.x & 63;
    const int gp   = lane >> 3;              // 0..7
    const int o    = lane & 7;               // q-octet
    const int g    = wave * 8 + gp;          // 0..31

    const unsigned short* src = partials + (size_t)row * NSL * 64;
    float s[8] = {0.f, 0.f, 0.f, 0.f, 0.f, 0.f, 0.f, 0.f};
#pragma unroll
    for (int i = 0; i < 8; i++) {
        const int slc = g + 32 * i;
        const short8 v = *(const short8*)(src + (size_t)slc * 64 + o * 8);
#pragma unroll
        for (int j = 0; j < 8; j++) s[j] += bf2f((unsigned short)v[j]);
    }
    // reduce across lane bits 3..5 (the 8 slice-groups within the wave)
#pragma unroll
    for (int off = 8; off <= 32; off <<= 1)
#pragma unroll
        for (int j = 0; j < 8; j++) s[j] += __shfl_xor(s[j], off, 64);
    if (lane < 8)
#pragma unroll
        for (int j = 0; j < 8; j++) red[wave][lane * 8 + j] = s[j];
    __syncthreads();

    if (wave == 0) {
        float t = red[0][lane] + red[1][lane] + red[2][lane] + red[3][lane];
        t *= (1.0f / 1024.0f);
        float m = t;
#pragma unroll
        for (int off = 32; off; off >>= 1) m = fmaxf(m, __shfl_xor(m, off, 64));
        const float e = __expf(t - m);
        float sum = e;
#pragma unroll
        for (int off = 32; off; off >>= 1) sum += __shfl_xor(sum, off, 64);
        attn_out[(size_t)row * 64 + lane] = e / sum;
    }
}

// ---------------------------------------------------------------------------
// K3: out[b][p][f][n] = sum_q attn[b][n][p][q] * V[b][n][q][f].
// grid = (256 fchunks of 64, 2 b), block = 512 (8 waves: 4 p-strips x 2
// f-strips). V tile [64 q][64 f] fp32 staged via global_load_lds, double-
// buffered across n with counted vmcnt (prefetch survives the barrier).
// ---------------------------------------------------------------------------
__global__ __launch_bounds__(512, 4) void pv_kernel(
        const float* __restrict__ V, const float* __restrict__ attn,
        float* __restrict__ out) {
    __shared__ float vt[2][64 * 64];   // 2 x 16 KB
    const int b    = blockIdx.y;
    const int fc   = blockIdx.x * 64;
    const int w    = threadIdx.x >> 6;
    const int lane = threadIdx.x & 63;
    const int lrow = lane & 15;
    const int lg   = lane >> 4;
    const int pstrip = (w >> 1) * 16;
    const int fstrip = (w & 1) * 32;

    f32x4 acc[8][2];
#pragma unroll
    for (int n = 0; n < 8; n++)
#pragma unroll
        for (int ft = 0; ft < 2; ft++) acc[n][ft] = (f32x4){0.f, 0.f, 0.f, 0.f};

#define STAGE(BI, N)                                                          \
    {                                                                         \
        const float* Vn_ = V + (size_t)(b * 8 + (N)) * 64 * FDIM;             \
        _Pragma("unroll")                                                     \
        for (int c = 0; c < 2; c++) {                                         \
            const int row_ = w * 8 + c * 4 + lg;                              \
            const float* src_ = Vn_ + (size_t)row_ * FDIM + fc + lrow * 4;    \
            __builtin_amdgcn_global_load_lds(                                 \
                (const __attribute__((address_space(1))) void*)src_,          \
                (__attribute__((address_space(3))) void*)&vt[BI][row_ * 64 + lrow * 4], \
                16, 0, 0);                                                    \
        }                                                                     \
    }

    STAGE(0, 0);
#pragma unroll
    for (int n = 0; n < 8; n++) {
        const int cur = n & 1;
        // A fragments (attn row for this n) — issued before the prefetch so
        // vmcnt(2) below also covers them.
        const float* Ap = attn + (size_t)(b * 8 + n) * 4096 +
                          (size_t)(pstrip + lrow) * 64 + lg * 8;
        const float4 a00 = *(const float4*)(Ap);
        const float4 a01 = *(const float4*)(Ap + 4);
        const float4 a10 = *(const float4*)(Ap + 32);
        const float4 a11 = *(const float4*)(Ap + 36);

        if (n < 7) {
            STAGE(cur ^ 1, n + 1);
            asm volatile("s_waitcnt vmcnt(2)" ::: "memory");
        } else {
            asm volatile("s_waitcnt vmcnt(0)" ::: "memory");
        }
        __builtin_amdgcn_s_barrier();
        __builtin_amdgcn_sched_barrier(0);

        const short8 a0 = pack8(a00, a01);
        const short8 a1 = pack8(a10, a11);

#pragma unroll
        for (int ft = 0; ft < 2; ft++) {
#pragma unroll
            for (int kk = 0; kk < 2; kk++) {
                short8 bf;
#pragma unroll
                for (int j = 0; j < 8; j++) {
                    const float vv = vt[cur][(kk * 32 + lg * 8 + j) * 64 +
                                             fstrip + ft * 16 + lrow];
                    bf[j] = (short)f2bf(vv);
                }
                acc[n][ft] = __builtin_amdgcn_mfma_f32_16x16x32_bf16(
                    kk ? a1 : a0, bf, acc[n][ft], 0, 0, 0);
            }
        }
        // barrier before next round's prefetch overwrites nothing we still
        // read: prefetch targets the other buffer; reads of `cur` are done
        // (lgkm drained before MFMA consumed them).
        __builtin_amdgcn_s_barrier();
    }

#pragma unroll
    for (int ft = 0; ft < 2; ft++)
#pragma unroll
        for (int r = 0; r < 4; r++) {
            const int p = pstrip + lg * 4 + r;
            const int f = fc + fstrip + ft * 16 + lrow;
            float4 w0, w1;
            w0.x = acc[0][ft][r]; w0.y = acc[1][ft][r];
            w0.z = acc[2][ft][r]; w0.w = acc[3][ft][r];
            w1.x = acc[4][ft][r]; w1.y = acc[5][ft][r];
            w1.z = acc[6][ft][r]; w1.w = acc[7][ft][r];
            float* dst = out + ((size_t)(b * 64 + p) * FDIM + f) * 8;
            *(float4*)dst       = w0;
            *(float4*)(dst + 4) = w1;
        }
#undef STAGE
}

extern "C" void kernel_launch(void* const* d_in, const int* in_sizes, int n_in,
                              void* d_out, int out_size, void* d_ws, size_t ws_size,
                              hipStream_t stream) {
    const float* Q = (const float*)d_in[0];
    const float* K = (const float*)d_in[1];
    const float* V = (const float*)d_in[2];
    float* out  = (float*)d_out;
    float* attn = out + OUT0;                      // [b][n][p][q] fp32
    unsigned short* partials = (unsigned short*)d_ws;  // 16*64*256*64 bf16 = 32 MB

    qk_kernel<<<dim3(64, 16), 256, 0, stream>>>(Q, K, partials);
    softmax_kernel<<<1024, 256, 0, stream>>>(partials, attn);
    pv_kernel<<<dim3(256, 2), 512, 0, stream>>>(V, attn, out);
}